// Round 4
// baseline (148.143 us; speedup 1.0000x reference)
//
#include <hip/hip_runtime.h>
#include <stdint.h>

typedef unsigned short u16;
typedef __attribute__((ext_vector_type(8))) __bf16 bf16x8;
typedef __attribute__((ext_vector_type(4))) float f32x4;
typedef __attribute__((ext_vector_type(16))) float f32x16;

#define D_IN 1024
#define NH 16
#define DH 64
#define BATCH 2
#define SEQ 2048

// log2(e)/sqrt(64): folded into Q at the QKV-projection epilogue so the
// attention kernel can use v_exp_f32 (2^x) directly with NO per-score scaling.
#define QSCL 0.1803368801111244f

#define GLD_LDS16(gp, lp)                                                              \
  __builtin_amdgcn_global_load_lds((__attribute__((address_space(1))) const void*)(gp), \
                                   (__attribute__((address_space(3))) void*)(lp), 16, 0, 0)

__device__ __forceinline__ u16 f2b(float f) {
  union { float ff; uint32_t u; } v; v.ff = f;
  return (u16)((v.u + 0x7fffu + ((v.u >> 16) & 1u)) >> 16);
}

__device__ __forceinline__ float swap32f(float v) { return __shfl_xor(v, 32, 64); }

__device__ __forceinline__ uint32_t cvtpk(float a, float b) {
  uint32_t r;
  asm("v_cvt_pk_bf16_f32 %0, %1, %2" : "=v"(r) : "v"(a), "v"(b));
  return r;
}
__device__ __forceinline__ float fexp2(float x) {
  float r;
  asm("v_exp_f32 %0, %1" : "=v"(r) : "v"(x));
  return r;
}

// ---------------- 1) fused prep: x->bf16  +  W->W^T bf16 ----------------
__global__ __launch_bounds__(256)
void prep_kernel(const float* __restrict__ x, u16* __restrict__ xb,
                 const float* __restrict__ W0, const float* __restrict__ W1,
                 const float* __restrict__ W2, const float* __restrict__ W3,
                 u16* __restrict__ T0, u16* __restrict__ T1,
                 u16* __restrict__ T2, u16* __restrict__ T3) {
  __shared__ float tile[32][33];
  if (blockIdx.x < 4096) {
    const int i = (blockIdx.x * 256 + threadIdx.x) * 4;
    const float4 v = *(const float4*)(x + i);
    uint2 pack;
    pack.x = (uint32_t)f2b(v.x) | ((uint32_t)f2b(v.y) << 16);
    pack.y = (uint32_t)f2b(v.z) | ((uint32_t)f2b(v.w) << 16);
    *(uint2*)(xb + i) = pack;
  } else {
    const int bid2 = blockIdx.x - 4096;
    const float* W; u16* T;
    switch (bid2 >> 10) {
      case 0: W = W0; T = T0; break;
      case 1: W = W1; T = T1; break;
      case 2: W = W2; T = T2; break;
      default: W = W3; T = T3; break;
    }
    const int rem = bid2 & 1023;
    const int n0 = (rem >> 5) * 32, k0 = (rem & 31) * 32;
    const int tx = threadIdx.x & 31, ty = threadIdx.x >> 5;
    #pragma unroll
    for (int i = 0; i < 32; i += 8)
      tile[ty + i][tx] = W[(size_t)(k0 + ty + i) * D_IN + n0 + tx];
    __syncthreads();
    #pragma unroll
    for (int i = 0; i < 32; i += 8)
      T[(size_t)(n0 + ty + i) * D_IN + k0 + tx] = f2b(tile[tx][ty + i]);
  }
}

// ---------------- 2) QKV projection GEMM ----------------
// V is stored k-permuted (swap bits 2<->3 of seq index within each 16-block) so
// the attention PV step needs NO cross-lane P redistribution.
__global__ __launch_bounds__(256)
void gemm_qkv_kernel(const u16* __restrict__ Xb,
                     const u16* __restrict__ WqT, const u16* __restrict__ WkT,
                     const u16* __restrict__ WvT,
                     u16* __restrict__ Qo, u16* __restrict__ Ko, u16* __restrict__ Vt) {
  __shared__ u16 As[128 * 32];
  __shared__ u16 Bs[128 * 32];
  const int which = blockIdx.z;
  const u16* Bt = (which == 0) ? WqT : (which == 1) ? WkT : WvT;

  const int tid = threadIdx.x;
  const int lane = tid & 63;
  const int w = tid >> 6;
  const int bm = blockIdx.x * 128;
  const int bn = blockIdx.y * 128;
  const int wr = w >> 1, wc = w & 1;
  const int g = lane >> 4, lm = lane & 15;
  const int srow = lane >> 2;
  const int scol = (lane & 3) * 8;

  const f32x4 zero = {0.f, 0.f, 0.f, 0.f};
  f32x4 acc[4][4];
  #pragma unroll
  for (int i = 0; i < 4; ++i)
    #pragma unroll
    for (int n = 0; n < 4; ++n) acc[i][n] = zero;

  for (int k0 = 0; k0 < D_IN; k0 += 32) {
    __syncthreads();
    #pragma unroll
    for (int L = 0; L < 2; ++L) {
      const int chunk = w * 2 + L;
      const int r = chunk * 16 + srow;
      GLD_LDS16(Xb + (size_t)(bm + r) * D_IN + k0 + scol, As + chunk * 512);
      GLD_LDS16(Bt + (size_t)(bn + r) * D_IN + k0 + scol, Bs + chunk * 512);
    }
    __syncthreads();

    bf16x8 af[4], bf[4];
    #pragma unroll
    for (int i = 0; i < 4; ++i)
      af[i] = *(const bf16x8*)(As + (wr * 64 + i * 16 + lm) * 32 + g * 8);
    #pragma unroll
    for (int n = 0; n < 4; ++n)
      bf[n] = *(const bf16x8*)(Bs + (wc * 64 + n * 16 + lm) * 32 + g * 8);
    #pragma unroll
    for (int i = 0; i < 4; ++i)
      #pragma unroll
      for (int n = 0; n < 4; ++n)
        acc[i][n] = __builtin_amdgcn_mfma_f32_16x16x32_bf16(af[i], bf[n], acc[i][n], 0, 0, 0);
  }

  const float oscale = (which == 0) ? QSCL : 1.0f;
  #pragma unroll
  for (int i = 0; i < 4; ++i) {
    #pragma unroll
    for (int n = 0; n < 4; ++n) {
      #pragma unroll
      for (int r = 0; r < 4; ++r) {
        const int m = bm + wr * 64 + i * 16 + g * 4 + r;
        const int c = bn + wc * 64 + n * 16 + lm;
        const int b = m >> 11, nn = m & (SEQ - 1);
        const int h = c >> 6, d = c & (DH - 1);
        const u16 val = f2b(acc[i][n][r] * oscale);
        if (which == 2) {
          const int np = (nn & ~15) | (nn & 3) | ((nn & 8) >> 1) | ((nn & 4) << 1);
          Vt[(size_t)((b * NH + h) * DH + d) * SEQ + np] = val;
        } else if (which == 0) {
          Qo[(size_t)((b * NH + h) * SEQ + nn) * DH + d] = val;
        } else {
          Ko[(size_t)((b * NH + h) * SEQ + nn) * DH + d] = val;
        }
      }
    }
  }
}

// ---------------- 3) causal flash attention: fixed-max, 4-way split-k ----------------
// 1024 blocks x 256 thr (4 waves) = 4 blocks/CU, 4 waves/SIMD. Block = one q-tile
// pair (jj, 63-jj) -> exactly 65 k-tiles, split stride-4 across the 4 waves.
// Fixed softmax max (=0) -> partials merge by pure addition in LDS.
// bid%8 == head%8 pins each head's K/V to one XCD's L2.
__global__ __launch_bounds__(256, 4)
void attn4_kernel(const u16* __restrict__ Qb, const u16* __restrict__ Kb,
                  const u16* __restrict__ Vt, u16* __restrict__ Ctx) {
  __shared__ float mbuf[4][32][64];   // [wave][q][d], chunk-XOR-swizzled
  __shared__ float lbuf[4][32];

  const int tid = threadIdx.x;
  const int lane = tid & 63;
  const int kw = tid >> 6;             // wave = split-k slot 0..3
  const int ql = lane & 31;
  const int hi = lane >> 5;
  const int bid = blockIdx.x;
  const int c = bid & 7;
  const int r = bid >> 3;              // 0..127
  const int jj = r & 31;               // pair index
  const int bh = c + 8 * (r >> 5);     // 0..31
  const int b = bh >> 4, h = bh & 15;

  const u16* Q = Qb + (size_t)bh * SEQ * DH;
  const u16* K = Kb + (size_t)bh * SEQ * DH;
  const u16* V = Vt + (size_t)bh * DH * SEQ;  // [d][n], n k-permuted

  // per-lane invariant bases
  const u16* kbase = K + (size_t)ql * DH + hi * 8;          // + t*32*DH
  const u16* v0base = V + (size_t)ql * SEQ + hi * 8;        // + t*32
  const u16* v1base = V + (size_t)(32 + ql) * SEQ + hi * 8; // + t*32

  #pragma unroll 1
  for (int pass = 0; pass < 2; ++pass) {
    const int qt = pass ? (63 - jj) : jj;
    const int qb0 = qt * 32;

    bf16x8 qf[4];
    #pragma unroll
    for (int st = 0; st < 4; ++st)
      qf[st] = *(const bf16x8*)(Q + (size_t)(qb0 + ql) * DH + st * 16 + hi * 8);

    f32x16 ctx0 = {0,0,0,0,0,0,0,0,0,0,0,0,0,0,0,0};
    f32x16 ctx1 = {0,0,0,0,0,0,0,0,0,0,0,0,0,0,0,0};
    float lacc[4] = {0.f, 0.f, 0.f, 0.f};

    bf16x8 kf[4], vf[4];
    if (kw <= qt) {
      // prologue load: tile kw
      {
        const u16* kp = kbase + (size_t)kw * 32 * DH;
        #pragma unroll
        for (int st = 0; st < 4; ++st) kf[st] = *(const bf16x8*)(kp + st * 16);
        const u16* vp0 = v0base + kw * 32;
        const u16* vp1 = v1base + kw * 32;
        vf[0] = *(const bf16x8*)vp0;        vf[1] = *(const bf16x8*)vp1;
        vf[2] = *(const bf16x8*)(vp0 + 16); vf[3] = *(const bf16x8*)(vp1 + 16);
      }
      #pragma unroll 1
      for (int t = kw; t <= qt; t += 4) {
        // ---- QK^T (S^T: key-in-reg, q-in-lane) ----
        f32x16 s = {0,0,0,0,0,0,0,0,0,0,0,0,0,0,0,0};
        #pragma unroll
        for (int st = 0; st < 4; ++st)
          s = __builtin_amdgcn_mfma_f32_32x32x16_bf16(kf[st], qf[st], s, 0, 0, 0);

        // prefetch next tile's K (kf dead after QK); clamped reload on last iter
        const int tn = (t + 4 <= qt) ? (t + 4) : qt;
        {
          const u16* kp = kbase + (size_t)tn * 32 * DH;
          #pragma unroll
          for (int st = 0; st < 4; ++st) kf[st] = *(const bf16x8*)(kp + st * 16);
        }

        // ---- softmax (fixed max = 0) ----
        float p[16];
        if (t == qt) {  // diagonal tile: causal mask (wave-uniform branch)
          #pragma unroll
          for (int cr = 0; cr < 16; ++cr) {
            const int kl = ((cr & 3) + 8 * (cr >> 2)) + 4 * hi;
            p[cr] = (kl > ql) ? 0.f : fexp2(s[cr]);
          }
        } else {
          #pragma unroll
          for (int cr = 0; cr < 16; ++cr) p[cr] = fexp2(s[cr]);
        }
        #pragma unroll
        for (int cr = 0; cr < 16; ++cr) lacc[cr & 3] += p[cr];

        // ---- PV: V stored k-permuted -> natural reg order IS the B-fragment ----
        #pragma unroll
        for (int ks = 0; ks < 2; ++ks) {
          uint4 pw;
          pw.x = cvtpk(p[ks * 8 + 0], p[ks * 8 + 1]);
          pw.y = cvtpk(p[ks * 8 + 2], p[ks * 8 + 3]);
          pw.z = cvtpk(p[ks * 8 + 4], p[ks * 8 + 5]);
          pw.w = cvtpk(p[ks * 8 + 6], p[ks * 8 + 7]);
          union { uint4 u; bf16x8 v; } pa; pa.u = pw;
          ctx0 = __builtin_amdgcn_mfma_f32_32x32x16_bf16(vf[ks * 2 + 0], pa.v, ctx0, 0, 0, 0);
          ctx1 = __builtin_amdgcn_mfma_f32_32x32x16_bf16(vf[ks * 2 + 1], pa.v, ctx1, 0, 0, 0);
        }

        // prefetch next tile's V (vf dead after PV)
        {
          const u16* vp0 = v0base + tn * 32;
          const u16* vp1 = v1base + tn * 32;
          vf[0] = *(const bf16x8*)vp0;        vf[1] = *(const bf16x8*)vp1;
          vf[2] = *(const bf16x8*)(vp0 + 16); vf[3] = *(const bf16x8*)(vp1 + 16);
        }
      }
    }

    // ---- 4-way split-k merge (fixed max -> pure addition) ----
    const float lloc = (lacc[0] + lacc[1]) + (lacc[2] + lacc[3]);
    const float lwv = lloc + swap32f(lloc);

    // write partial ctx: chunk ch = d/4, stored at ch ^ (q&15) (bank-conflict-free)
    #pragma unroll
    for (int grp = 0; grp < 4; ++grp) {
      const int ch = grp * 2 + hi;
      f32x4 t0 = {ctx0[grp * 4 + 0], ctx0[grp * 4 + 1], ctx0[grp * 4 + 2], ctx0[grp * 4 + 3]};
      f32x4 t1 = {ctx1[grp * 4 + 0], ctx1[grp * 4 + 1], ctx1[grp * 4 + 2], ctx1[grp * 4 + 3]};
      *(f32x4*)&mbuf[kw][ql][(ch ^ ql) * 4 & 63]       = t0;
      *(f32x4*)&mbuf[kw][ql][((ch + 8) ^ ql) * 4 & 63] = t1;
    }
    if (lane < 32) lbuf[kw][ql] = lwv;
    __syncthreads();

    // each wave sums d-slice [kw*16 + hi*8, +8) over the 4 partials
    {
      const int ch0 = kw * 4 + hi * 2;
      f32x4 a0 = {0.f, 0.f, 0.f, 0.f}, a1 = {0.f, 0.f, 0.f, 0.f};
      #pragma unroll
      for (int p2 = 0; p2 < 4; ++p2) {
        a0 += *(const f32x4*)&mbuf[p2][ql][(ch0 ^ ql) * 4 & 63];
        a1 += *(const f32x4*)&mbuf[p2][ql][((ch0 + 1) ^ ql) * 4 & 63];
      }
      const float lt = (lbuf[0][ql] + lbuf[1][ql]) + (lbuf[2][ql] + lbuf[3][ql]);
      const float inv = __builtin_amdgcn_rcpf(lt);
      uint4 pw;
      pw.x = cvtpk(a0[0] * inv, a0[1] * inv);
      pw.y = cvtpk(a0[2] * inv, a0[3] * inv);
      pw.z = cvtpk(a1[0] * inv, a1[1] * inv);
      pw.w = cvtpk(a1[2] * inv, a1[3] * inv);
      *(uint4*)(Ctx + (size_t)(b * SEQ + qb0 + ql) * 1024 + h * 64 + kw * 16 + hi * 8) = pw;
    }
    __syncthreads();  // protect mbuf/lbuf reuse in next pass
  }
}

// ---------------- 4) output projection + bias (fp32 out) ----------------
__global__ __launch_bounds__(256)
void gemm_out_kernel(const u16* __restrict__ Ctx, const u16* __restrict__ WoT,
                     const float* __restrict__ bo, float* __restrict__ out) {
  __shared__ u16 As[128 * 32];
  __shared__ u16 Bs[128 * 32];
  const int tid = threadIdx.x;
  const int lane = tid & 63;
  const int w = tid >> 6;
  const int bm = blockIdx.x * 128;
  const int bn = blockIdx.y * 128;
  const int wr = w >> 1, wc = w & 1;
  const int g = lane >> 4, lm = lane & 15;
  const int srow = lane >> 2;
  const int scol = (lane & 3) * 8;

  const f32x4 zero = {0.f, 0.f, 0.f, 0.f};
  f32x4 acc[4][4];
  #pragma unroll
  for (int i = 0; i < 4; ++i)
    #pragma unroll
    for (int n = 0; n < 4; ++n) acc[i][n] = zero;

  for (int k0 = 0; k0 < D_IN; k0 += 32) {
    __syncthreads();
    #pragma unroll
    for (int L = 0; L < 2; ++L) {
      const int chunk = w * 2 + L;
      const int r = chunk * 16 + srow;
      GLD_LDS16(Ctx + (size_t)(bm + r) * D_IN + k0 + scol, As + chunk * 512);
      GLD_LDS16(WoT + (size_t)(bn + r) * D_IN + k0 + scol, Bs + chunk * 512);
    }
    __syncthreads();

    bf16x8 af[4], bf[4];
    #pragma unroll
    for (int i = 0; i < 4; ++i)
      af[i] = *(const bf16x8*)(As + (wr * 64 + i * 16 + lm) * 32 + g * 8);
    #pragma unroll
    for (int n = 0; n < 4; ++n)
      bf[n] = *(const bf16x8*)(Bs + (wc * 64 + n * 16 + lm) * 32 + g * 8);
    #pragma unroll
    for (int i = 0; i < 4; ++i)
      #pragma unroll
      for (int n = 0; n < 4; ++n)
        acc[i][n] = __builtin_amdgcn_mfma_f32_16x16x32_bf16(af[i], bf[n], acc[i][n], 0, 0, 0);
  }

  #pragma unroll
  for (int i = 0; i < 4; ++i)
    #pragma unroll
    for (int n = 0; n < 4; ++n)
      #pragma unroll
      for (int r = 0; r < 4; ++r) {
        const int m = bm + wr * 64 + i * 16 + g * 4 + r;
        const int cidx = bn + wc * 64 + n * 16 + lm;
        out[(size_t)m * 1024 + cidx] = acc[i][n][r] + bo[cidx];
      }
}

extern "C" void kernel_launch(void* const* d_in, const int* in_sizes, int n_in,
                              void* d_out, int out_size, void* d_ws, size_t ws_size,
                              hipStream_t stream) {
  (void)in_sizes; (void)n_in; (void)out_size; (void)ws_size;
  const float* x  = (const float*)d_in[0];
  const float* Wq = (const float*)d_in[1];
  const float* Wk = (const float*)d_in[2];
  const float* Wv = (const float*)d_in[3];
  const float* Wo = (const float*)d_in[4];
  const float* bo = (const float*)d_in[5];
  float* out = (float*)d_out;

  char* ws = (char*)d_ws;
  u16* xb  = (u16*)(ws);
  u16* WqT = (u16*)(ws + (8u << 20));
  u16* WkT = (u16*)(ws + (10u << 20));
  u16* WvT = (u16*)(ws + (12u << 20));
  u16* WoT = (u16*)(ws + (14u << 20));
  u16* Qb  = (u16*)(ws + (16u << 20));
  u16* Kb  = (u16*)(ws + (24u << 20));
  u16* Vt  = (u16*)(ws + (32u << 20));
  u16* Ctx = xb;  // xb fully consumed by gemm_qkv before attn writes Ctx

  prep_kernel<<<dim3(8192), 256, 0, stream>>>(x, xb, Wq, Wk, Wv, Wo, WqT, WkT, WvT, WoT);
  gemm_qkv_kernel<<<dim3(32, 8, 3), 256, 0, stream>>>(xb, WqT, WkT, WvT, Qb, Kb, Vt);
  attn4_kernel<<<dim3(1024), 256, 0, stream>>>(Qb, Kb, Vt, Ctx);
  gemm_out_kernel<<<dim3(32, 8), 256, 0, stream>>>(Ctx, WoT, bo, out);
}

// Round 5
// 143.493 us; speedup vs baseline: 1.0324x; 1.0324x over previous
//
#include <hip/hip_runtime.h>
#include <stdint.h>

typedef unsigned short u16;
typedef __attribute__((ext_vector_type(8))) __bf16 bf16x8;
typedef __attribute__((ext_vector_type(4))) float f32x4;
typedef __attribute__((ext_vector_type(16))) float f32x16;

#define D_IN 1024
#define NH 16
#define DH 64
#define BATCH 2
#define SEQ 2048

// log2(e)/sqrt(64): folded into Q at the QKV-projection epilogue so the
// attention kernel can use v_exp_f32 (2^x) directly with NO per-score scaling.
#define QSCL 0.1803368801111244f

#define GLD_LDS16(gp, lp)                                                              \
  __builtin_amdgcn_global_load_lds((__attribute__((address_space(1))) const void*)(gp), \
                                   (__attribute__((address_space(3))) void*)(lp), 16, 0, 0)

__device__ __forceinline__ u16 f2b(float f) {
  union { float ff; uint32_t u; } v; v.ff = f;
  return (u16)((v.u + 0x7fffu + ((v.u >> 16) & 1u)) >> 16);
}

__device__ __forceinline__ float swap32f(float v) { return __shfl_xor(v, 32, 64); }

__device__ __forceinline__ uint32_t cvtpk(float a, float b) {
  uint32_t r;
  asm("v_cvt_pk_bf16_f32 %0, %1, %2" : "=v"(r) : "v"(a), "v"(b));
  return r;
}
__device__ __forceinline__ float fexp2(float x) {
  float r;
  asm("v_exp_f32 %0, %1" : "=v"(r) : "v"(x));
  return r;
}

// ---------------- 1) fused prep: x->bf16  +  W->W^T bf16 ----------------
__global__ __launch_bounds__(256)
void prep_kernel(const float* __restrict__ x, u16* __restrict__ xb,
                 const float* __restrict__ W0, const float* __restrict__ W1,
                 const float* __restrict__ W2, const float* __restrict__ W3,
                 u16* __restrict__ T0, u16* __restrict__ T1,
                 u16* __restrict__ T2, u16* __restrict__ T3) {
  __shared__ float tile[32][33];
  if (blockIdx.x < 4096) {
    const int i = (blockIdx.x * 256 + threadIdx.x) * 4;
    const float4 v = *(const float4*)(x + i);
    uint2 pack;
    pack.x = (uint32_t)f2b(v.x) | ((uint32_t)f2b(v.y) << 16);
    pack.y = (uint32_t)f2b(v.z) | ((uint32_t)f2b(v.w) << 16);
    *(uint2*)(xb + i) = pack;
  } else {
    const int bid2 = blockIdx.x - 4096;
    const float* W; u16* T;
    switch (bid2 >> 10) {
      case 0: W = W0; T = T0; break;
      case 1: W = W1; T = T1; break;
      case 2: W = W2; T = T2; break;
      default: W = W3; T = T3; break;
    }
    const int rem = bid2 & 1023;
    const int n0 = (rem >> 5) * 32, k0 = (rem & 31) * 32;
    const int tx = threadIdx.x & 31, ty = threadIdx.x >> 5;
    #pragma unroll
    for (int i = 0; i < 32; i += 8)
      tile[ty + i][tx] = W[(size_t)(k0 + ty + i) * D_IN + n0 + tx];
    __syncthreads();
    #pragma unroll
    for (int i = 0; i < 32; i += 8)
      T[(size_t)(n0 + ty + i) * D_IN + k0 + tx] = f2b(tile[tx][ty + i]);
  }
}

// ---------------- 2) QKV projection GEMM ----------------
// V is stored k-permuted (swap bits 2<->3 of seq index within each 16-block) so
// the attention PV step needs NO cross-lane P redistribution.
__global__ __launch_bounds__(256)
void gemm_qkv_kernel(const u16* __restrict__ Xb,
                     const u16* __restrict__ WqT, const u16* __restrict__ WkT,
                     const u16* __restrict__ WvT,
                     u16* __restrict__ Qo, u16* __restrict__ Ko, u16* __restrict__ Vt) {
  __shared__ u16 As[128 * 32];
  __shared__ u16 Bs[128 * 32];
  const int which = blockIdx.z;
  const u16* Bt = (which == 0) ? WqT : (which == 1) ? WkT : WvT;

  const int tid = threadIdx.x;
  const int lane = tid & 63;
  const int w = tid >> 6;
  const int bm = blockIdx.x * 128;
  const int bn = blockIdx.y * 128;
  const int wr = w >> 1, wc = w & 1;
  const int g = lane >> 4, lm = lane & 15;
  const int srow = lane >> 2;
  const int scol = (lane & 3) * 8;

  const f32x4 zero = {0.f, 0.f, 0.f, 0.f};
  f32x4 acc[4][4];
  #pragma unroll
  for (int i = 0; i < 4; ++i)
    #pragma unroll
    for (int n = 0; n < 4; ++n) acc[i][n] = zero;

  for (int k0 = 0; k0 < D_IN; k0 += 32) {
    __syncthreads();
    #pragma unroll
    for (int L = 0; L < 2; ++L) {
      const int chunk = w * 2 + L;
      const int r = chunk * 16 + srow;
      GLD_LDS16(Xb + (size_t)(bm + r) * D_IN + k0 + scol, As + chunk * 512);
      GLD_LDS16(Bt + (size_t)(bn + r) * D_IN + k0 + scol, Bs + chunk * 512);
    }
    __syncthreads();

    bf16x8 af[4], bf[4];
    #pragma unroll
    for (int i = 0; i < 4; ++i)
      af[i] = *(const bf16x8*)(As + (wr * 64 + i * 16 + lm) * 32 + g * 8);
    #pragma unroll
    for (int n = 0; n < 4; ++n)
      bf[n] = *(const bf16x8*)(Bs + (wc * 64 + n * 16 + lm) * 32 + g * 8);
    #pragma unroll
    for (int i = 0; i < 4; ++i)
      #pragma unroll
      for (int n = 0; n < 4; ++n)
        acc[i][n] = __builtin_amdgcn_mfma_f32_16x16x32_bf16(af[i], bf[n], acc[i][n], 0, 0, 0);
  }

  const float oscale = (which == 0) ? QSCL : 1.0f;
  #pragma unroll
  for (int i = 0; i < 4; ++i) {
    #pragma unroll
    for (int n = 0; n < 4; ++n) {
      #pragma unroll
      for (int r = 0; r < 4; ++r) {
        const int m = bm + wr * 64 + i * 16 + g * 4 + r;
        const int c = bn + wc * 64 + n * 16 + lm;
        const int b = m >> 11, nn = m & (SEQ - 1);
        const int h = c >> 6, d = c & (DH - 1);
        const u16 val = f2b(acc[i][n][r] * oscale);
        if (which == 2) {
          const int np = (nn & ~15) | (nn & 3) | ((nn & 8) >> 1) | ((nn & 4) << 1);
          Vt[(size_t)((b * NH + h) * DH + d) * SEQ + np] = val;
        } else if (which == 0) {
          Qo[(size_t)((b * NH + h) * SEQ + nn) * DH + d] = val;
        } else {
          Ko[(size_t)((b * NH + h) * SEQ + nn) * DH + d] = val;
        }
      }
    }
  }
}

// ---------------- 3) causal flash attention: fixed-max, 4-way split-k ----------------
// 1024 blocks x 256 thr (4 waves). Block = one q-tile pair (jj, 63-jj) -> exactly
// 65 k-tiles, split stride-4 across the 4 waves. Fixed softmax max (=0) ->
// partials merge by pure addition in LDS. bid%8 == head%8 pins K/V to one XCD L2.
// NOTE: plain launch_bounds — the (256,4) min-waves hint drove the allocator to
// the 64-VGPR tier and spilled the ~110-reg live set to scratch (r4: WRITE_SIZE
// 8->33 MB, VALUBusy 13%). Compiler picks ~120 regs here (r3 evidence).
__global__ __launch_bounds__(256)
void attn4_kernel(const u16* __restrict__ Qb, const u16* __restrict__ Kb,
                  const u16* __restrict__ Vt, u16* __restrict__ Ctx) {
  __shared__ float mbuf[4][32][64];   // [wave][q][d], chunk-XOR-swizzled
  __shared__ float lbuf[4][32];

  const int tid = threadIdx.x;
  const int lane = tid & 63;
  const int kw = tid >> 6;             // wave = split-k slot 0..3
  const int ql = lane & 31;
  const int hi = lane >> 5;
  const int bid = blockIdx.x;
  const int c = bid & 7;
  const int r = bid >> 3;              // 0..127
  const int jj = r & 31;               // pair index
  const int bh = c + 8 * (r >> 5);     // 0..31
  const int b = bh >> 4, h = bh & 15;

  const u16* Q = Qb + (size_t)bh * SEQ * DH;
  const u16* K = Kb + (size_t)bh * SEQ * DH;
  const u16* V = Vt + (size_t)bh * DH * SEQ;  // [d][n], n k-permuted

  // per-lane invariant bases
  const u16* kbase = K + (size_t)ql * DH + hi * 8;          // + t*32*DH
  const u16* v0base = V + (size_t)ql * SEQ + hi * 8;        // + t*32
  const u16* v1base = V + (size_t)(32 + ql) * SEQ + hi * 8; // + t*32

  #pragma unroll 1
  for (int pass = 0; pass < 2; ++pass) {
    const int qt = pass ? (63 - jj) : jj;
    const int qb0 = qt * 32;

    bf16x8 qf[4];
    #pragma unroll
    for (int st = 0; st < 4; ++st)
      qf[st] = *(const bf16x8*)(Q + (size_t)(qb0 + ql) * DH + st * 16 + hi * 8);

    f32x16 ctx0 = {0,0,0,0,0,0,0,0,0,0,0,0,0,0,0,0};
    f32x16 ctx1 = {0,0,0,0,0,0,0,0,0,0,0,0,0,0,0,0};
    float lacc[4] = {0.f, 0.f, 0.f, 0.f};

    bf16x8 kf[4], vf[4];
    if (kw <= qt) {
      // prologue load: tile kw
      {
        const u16* kp = kbase + (size_t)kw * 32 * DH;
        #pragma unroll
        for (int st = 0; st < 4; ++st) kf[st] = *(const bf16x8*)(kp + st * 16);
        const u16* vp0 = v0base + kw * 32;
        const u16* vp1 = v1base + kw * 32;
        vf[0] = *(const bf16x8*)vp0;        vf[1] = *(const bf16x8*)vp1;
        vf[2] = *(const bf16x8*)(vp0 + 16); vf[3] = *(const bf16x8*)(vp1 + 16);
      }
      #pragma unroll 1
      for (int t = kw; t <= qt; t += 4) {
        // ---- QK^T (S^T: key-in-reg, q-in-lane) ----
        f32x16 s = {0,0,0,0,0,0,0,0,0,0,0,0,0,0,0,0};
        #pragma unroll
        for (int st = 0; st < 4; ++st)
          s = __builtin_amdgcn_mfma_f32_32x32x16_bf16(kf[st], qf[st], s, 0, 0, 0);

        // prefetch next tile's K (kf dead after QK); clamped reload on last iter
        const int tn = (t + 4 <= qt) ? (t + 4) : qt;
        {
          const u16* kp = kbase + (size_t)tn * 32 * DH;
          #pragma unroll
          for (int st = 0; st < 4; ++st) kf[st] = *(const bf16x8*)(kp + st * 16);
        }

        // ---- softmax (fixed max = 0) ----
        float p[16];
        if (t == qt) {  // diagonal tile: causal mask (wave-uniform branch)
          #pragma unroll
          for (int cr = 0; cr < 16; ++cr) {
            const int kl = ((cr & 3) + 8 * (cr >> 2)) + 4 * hi;
            p[cr] = (kl > ql) ? 0.f : fexp2(s[cr]);
          }
        } else {
          #pragma unroll
          for (int cr = 0; cr < 16; ++cr) p[cr] = fexp2(s[cr]);
        }
        #pragma unroll
        for (int cr = 0; cr < 16; ++cr) lacc[cr & 3] += p[cr];

        // ---- PV: V stored k-permuted -> natural reg order IS the B-fragment ----
        #pragma unroll
        for (int ks = 0; ks < 2; ++ks) {
          uint4 pw;
          pw.x = cvtpk(p[ks * 8 + 0], p[ks * 8 + 1]);
          pw.y = cvtpk(p[ks * 8 + 2], p[ks * 8 + 3]);
          pw.z = cvtpk(p[ks * 8 + 4], p[ks * 8 + 5]);
          pw.w = cvtpk(p[ks * 8 + 6], p[ks * 8 + 7]);
          union { uint4 u; bf16x8 v; } pa; pa.u = pw;
          ctx0 = __builtin_amdgcn_mfma_f32_32x32x16_bf16(vf[ks * 2 + 0], pa.v, ctx0, 0, 0, 0);
          ctx1 = __builtin_amdgcn_mfma_f32_32x32x16_bf16(vf[ks * 2 + 1], pa.v, ctx1, 0, 0, 0);
        }

        // prefetch next tile's V (vf dead after PV)
        {
          const u16* vp0 = v0base + tn * 32;
          const u16* vp1 = v1base + tn * 32;
          vf[0] = *(const bf16x8*)vp0;        vf[1] = *(const bf16x8*)vp1;
          vf[2] = *(const bf16x8*)(vp0 + 16); vf[3] = *(const bf16x8*)(vp1 + 16);
        }
      }
    }

    // ---- 4-way split-k merge (fixed max -> pure addition) ----
    const float lloc = (lacc[0] + lacc[1]) + (lacc[2] + lacc[3]);
    const float lwv = lloc + swap32f(lloc);

    // write partial ctx: chunk ch = d/4, stored at ch ^ (q&15) (bank-conflict-free)
    #pragma unroll
    for (int grp = 0; grp < 4; ++grp) {
      const int ch = grp * 2 + hi;
      f32x4 t0 = {ctx0[grp * 4 + 0], ctx0[grp * 4 + 1], ctx0[grp * 4 + 2], ctx0[grp * 4 + 3]};
      f32x4 t1 = {ctx1[grp * 4 + 0], ctx1[grp * 4 + 1], ctx1[grp * 4 + 2], ctx1[grp * 4 + 3]};
      *(f32x4*)&mbuf[kw][ql][(ch ^ ql) * 4 & 63]       = t0;
      *(f32x4*)&mbuf[kw][ql][((ch + 8) ^ ql) * 4 & 63] = t1;
    }
    if (lane < 32) lbuf[kw][ql] = lwv;
    __syncthreads();

    // each wave sums d-slice [kw*16 + hi*8, +8) over the 4 partials
    {
      const int ch0 = kw * 4 + hi * 2;
      f32x4 a0 = {0.f, 0.f, 0.f, 0.f}, a1 = {0.f, 0.f, 0.f, 0.f};
      #pragma unroll
      for (int p2 = 0; p2 < 4; ++p2) {
        a0 += *(const f32x4*)&mbuf[p2][ql][(ch0 ^ ql) * 4 & 63];
        a1 += *(const f32x4*)&mbuf[p2][ql][((ch0 + 1) ^ ql) * 4 & 63];
      }
      const float lt = (lbuf[0][ql] + lbuf[1][ql]) + (lbuf[2][ql] + lbuf[3][ql]);
      const float inv = __builtin_amdgcn_rcpf(lt);
      uint4 pw;
      pw.x = cvtpk(a0[0] * inv, a0[1] * inv);
      pw.y = cvtpk(a0[2] * inv, a0[3] * inv);
      pw.z = cvtpk(a1[0] * inv, a1[1] * inv);
      pw.w = cvtpk(a1[2] * inv, a1[3] * inv);
      *(uint4*)(Ctx + (size_t)(b * SEQ + qb0 + ql) * 1024 + h * 64 + kw * 16 + hi * 8) = pw;
    }
    __syncthreads();  // protect mbuf/lbuf reuse in next pass
  }
}

// ---------------- 4) output projection + bias (fp32 out) ----------------
__global__ __launch_bounds__(256)
void gemm_out_kernel(const u16* __restrict__ Ctx, const u16* __restrict__ WoT,
                     const float* __restrict__ bo, float* __restrict__ out) {
  __shared__ u16 As[128 * 32];
  __shared__ u16 Bs[128 * 32];
  const int tid = threadIdx.x;
  const int lane = tid & 63;
  const int w = tid >> 6;
  const int bm = blockIdx.x * 128;
  const int bn = blockIdx.y * 128;
  const int wr = w >> 1, wc = w & 1;
  const int g = lane >> 4, lm = lane & 15;
  const int srow = lane >> 2;
  const int scol = (lane & 3) * 8;

  const f32x4 zero = {0.f, 0.f, 0.f, 0.f};
  f32x4 acc[4][4];
  #pragma unroll
  for (int i = 0; i < 4; ++i)
    #pragma unroll
    for (int n = 0; n < 4; ++n) acc[i][n] = zero;

  for (int k0 = 0; k0 < D_IN; k0 += 32) {
    __syncthreads();
    #pragma unroll
    for (int L = 0; L < 2; ++L) {
      const int chunk = w * 2 + L;
      const int r = chunk * 16 + srow;
      GLD_LDS16(Ctx + (size_t)(bm + r) * D_IN + k0 + scol, As + chunk * 512);
      GLD_LDS16(WoT + (size_t)(bn + r) * D_IN + k0 + scol, Bs + chunk * 512);
    }
    __syncthreads();

    bf16x8 af[4], bf[4];
    #pragma unroll
    for (int i = 0; i < 4; ++i)
      af[i] = *(const bf16x8*)(As + (wr * 64 + i * 16 + lm) * 32 + g * 8);
    #pragma unroll
    for (int n = 0; n < 4; ++n)
      bf[n] = *(const bf16x8*)(Bs + (wc * 64 + n * 16 + lm) * 32 + g * 8);
    #pragma unroll
    for (int i = 0; i < 4; ++i)
      #pragma unroll
      for (int n = 0; n < 4; ++n)
        acc[i][n] = __builtin_amdgcn_mfma_f32_16x16x32_bf16(af[i], bf[n], acc[i][n], 0, 0, 0);
  }

  #pragma unroll
  for (int i = 0; i < 4; ++i)
    #pragma unroll
    for (int n = 0; n < 4; ++n)
      #pragma unroll
      for (int r = 0; r < 4; ++r) {
        const int m = bm + wr * 64 + i * 16 + g * 4 + r;
        const int cidx = bn + wc * 64 + n * 16 + lm;
        out[(size_t)m * 1024 + cidx] = acc[i][n][r] + bo[cidx];
      }
}

extern "C" void kernel_launch(void* const* d_in, const int* in_sizes, int n_in,
                              void* d_out, int out_size, void* d_ws, size_t ws_size,
                              hipStream_t stream) {
  (void)in_sizes; (void)n_in; (void)out_size; (void)ws_size;
  const float* x  = (const float*)d_in[0];
  const float* Wq = (const float*)d_in[1];
  const float* Wk = (const float*)d_in[2];
  const float* Wv = (const float*)d_in[3];
  const float* Wo = (const float*)d_in[4];
  const float* bo = (const float*)d_in[5];
  float* out = (float*)d_out;

  char* ws = (char*)d_ws;
  u16* xb  = (u16*)(ws);
  u16* WqT = (u16*)(ws + (8u << 20));
  u16* WkT = (u16*)(ws + (10u << 20));
  u16* WvT = (u16*)(ws + (12u << 20));
  u16* WoT = (u16*)(ws + (14u << 20));
  u16* Qb  = (u16*)(ws + (16u << 20));
  u16* Kb  = (u16*)(ws + (24u << 20));
  u16* Vt  = (u16*)(ws + (32u << 20));
  u16* Ctx = xb;  // xb fully consumed by gemm_qkv before attn writes Ctx

  prep_kernel<<<dim3(8192), 256, 0, stream>>>(x, xb, Wq, Wk, Wv, Wo, WqT, WkT, WvT, WoT);
  gemm_qkv_kernel<<<dim3(32, 8, 3), 256, 0, stream>>>(xb, WqT, WkT, WvT, Qb, Kb, Vt);
  attn4_kernel<<<dim3(1024), 256, 0, stream>>>(Qb, Kb, Vt, Ctx);
  gemm_out_kernel<<<dim3(32, 8), 256, 0, stream>>>(Ctx, WoT, bo, out);
}

// Round 6
// 103.385 us; speedup vs baseline: 1.4329x; 1.3880x over previous
//
#include <hip/hip_runtime.h>
#include <stdint.h>

typedef unsigned short u16;
typedef __attribute__((ext_vector_type(8))) __bf16 bf16x8;
typedef __attribute__((ext_vector_type(4))) float f32x4;
typedef __attribute__((ext_vector_type(16))) float f32x16;

#define D_IN 1024
#define NH 16
#define DH 64
#define BATCH 2
#define SEQ 2048

// log2(e)/sqrt(64): folded into Q at the QKV-projection epilogue so the
// attention kernel can use v_exp_f32 (2^x) directly with NO per-score scaling.
#define QSCL 0.1803368801111244f

#define GLD_LDS16(gp, lp)                                                              \
  __builtin_amdgcn_global_load_lds((__attribute__((address_space(1))) const void*)(gp), \
                                   (__attribute__((address_space(3))) void*)(lp), 16, 0, 0)

__device__ __forceinline__ u16 f2b(float f) {
  union { float ff; uint32_t u; } v; v.ff = f;
  return (u16)((v.u + 0x7fffu + ((v.u >> 16) & 1u)) >> 16);
}

__device__ __forceinline__ float swap32f(float v) { return __shfl_xor(v, 32, 64); }

__device__ __forceinline__ uint32_t cvtpk(float a, float b) {
  uint32_t r;
  asm("v_cvt_pk_bf16_f32 %0, %1, %2" : "=v"(r) : "v"(a), "v"(b));
  return r;
}
__device__ __forceinline__ float fexp2(float x) {
  float r;
  asm("v_exp_f32 %0, %1" : "=v"(r) : "v"(x));
  return r;
}

// ---------------- 1) fused prep: x->bf16  +  W->W^T bf16 ----------------
__global__ __launch_bounds__(256)
void prep_kernel(const float* __restrict__ x, u16* __restrict__ xb,
                 const float* __restrict__ W0, const float* __restrict__ W1,
                 const float* __restrict__ W2, const float* __restrict__ W3,
                 u16* __restrict__ T0, u16* __restrict__ T1,
                 u16* __restrict__ T2, u16* __restrict__ T3) {
  __shared__ float tile[32][33];
  if (blockIdx.x < 4096) {
    const int i = (blockIdx.x * 256 + threadIdx.x) * 4;
    const float4 v = *(const float4*)(x + i);
    uint2 pack;
    pack.x = (uint32_t)f2b(v.x) | ((uint32_t)f2b(v.y) << 16);
    pack.y = (uint32_t)f2b(v.z) | ((uint32_t)f2b(v.w) << 16);
    *(uint2*)(xb + i) = pack;
  } else {
    const int bid2 = blockIdx.x - 4096;
    const float* W; u16* T;
    switch (bid2 >> 10) {
      case 0: W = W0; T = T0; break;
      case 1: W = W1; T = T1; break;
      case 2: W = W2; T = T2; break;
      default: W = W3; T = T3; break;
    }
    const int rem = bid2 & 1023;
    const int n0 = (rem >> 5) * 32, k0 = (rem & 31) * 32;
    const int tx = threadIdx.x & 31, ty = threadIdx.x >> 5;
    #pragma unroll
    for (int i = 0; i < 32; i += 8)
      tile[ty + i][tx] = W[(size_t)(k0 + ty + i) * D_IN + n0 + tx];
    __syncthreads();
    #pragma unroll
    for (int i = 0; i < 32; i += 8)
      T[(size_t)(n0 + ty + i) * D_IN + k0 + tx] = f2b(tile[tx][ty + i]);
  }
}

// ---------------- 2) QKV projection GEMM ----------------
// Q/K/V are written in MFMA-FRAGMENT order:
//   Xf[bh][tile t][frag][lane][j]  (u16; frag stride 512, tile stride 2048)
// so each attention fragment load is base + lane*16B -> fully coalesced.
// Q/K (B/A operands of QK^T): frag=st (d>>4), lane=((d>>3)&1)*32 + (n&31), j=d&7.
// V (A operand of PV, k-order matched to P's register order):
//   slot (ks,hi,j) holds n = 16ks + 8*(j>>2) + 4*hi + (j&3);
//   frag = (n5>>4)*2 + (d>>5), lane = ((n5>>2)&1)*32 + (d&31), j = 4*((n5>>3)&1) + (n5&3).
__global__ __launch_bounds__(256)
void gemm_qkv_kernel(const u16* __restrict__ Xb,
                     const u16* __restrict__ WqT, const u16* __restrict__ WkT,
                     const u16* __restrict__ WvT,
                     u16* __restrict__ Qo, u16* __restrict__ Ko, u16* __restrict__ Vt) {
  __shared__ u16 As[128 * 32];
  __shared__ u16 Bs[128 * 32];
  const int which = blockIdx.z;
  const u16* Bt = (which == 0) ? WqT : (which == 1) ? WkT : WvT;

  const int tid = threadIdx.x;
  const int lane = tid & 63;
  const int w = tid >> 6;
  const int bm = blockIdx.x * 128;
  const int bn = blockIdx.y * 128;
  const int wr = w >> 1, wc = w & 1;
  const int g = lane >> 4, lm = lane & 15;
  const int srow = lane >> 2;
  const int scol = (lane & 3) * 8;

  const f32x4 zero = {0.f, 0.f, 0.f, 0.f};
  f32x4 acc[4][4];
  #pragma unroll
  for (int i = 0; i < 4; ++i)
    #pragma unroll
    for (int n = 0; n < 4; ++n) acc[i][n] = zero;

  for (int k0 = 0; k0 < D_IN; k0 += 32) {
    __syncthreads();
    #pragma unroll
    for (int L = 0; L < 2; ++L) {
      const int chunk = w * 2 + L;
      const int r = chunk * 16 + srow;
      GLD_LDS16(Xb + (size_t)(bm + r) * D_IN + k0 + scol, As + chunk * 512);
      GLD_LDS16(Bt + (size_t)(bn + r) * D_IN + k0 + scol, Bs + chunk * 512);
    }
    __syncthreads();

    bf16x8 af[4], bf[4];
    #pragma unroll
    for (int i = 0; i < 4; ++i)
      af[i] = *(const bf16x8*)(As + (wr * 64 + i * 16 + lm) * 32 + g * 8);
    #pragma unroll
    for (int n = 0; n < 4; ++n)
      bf[n] = *(const bf16x8*)(Bs + (wc * 64 + n * 16 + lm) * 32 + g * 8);
    #pragma unroll
    for (int i = 0; i < 4; ++i)
      #pragma unroll
      for (int n = 0; n < 4; ++n)
        acc[i][n] = __builtin_amdgcn_mfma_f32_16x16x32_bf16(af[i], bf[n], acc[i][n], 0, 0, 0);
  }

  const float oscale = (which == 0) ? QSCL : 1.0f;
  #pragma unroll
  for (int i = 0; i < 4; ++i) {
    #pragma unroll
    for (int n = 0; n < 4; ++n) {
      #pragma unroll
      for (int r = 0; r < 4; ++r) {
        const int m = bm + wr * 64 + i * 16 + g * 4 + r;
        const int c = bn + wc * 64 + n * 16 + lm;
        const int b = m >> 11, nn = m & (SEQ - 1);
        const int h = c >> 6, d = c & (DH - 1);
        const int bh = b * NH + h;
        const int t = nn >> 5;
        const u16 val = f2b(acc[i][n][r] * oscale);
        if (which == 2) {
          const int n5 = nn & 31;
          const int f = (n5 >> 4) * 2 + (d >> 5);
          const int lane2 = ((n5 >> 2) & 1) * 32 + (d & 31);
          const int j = ((n5 >> 3) & 1) * 4 + (n5 & 3);
          Vt[((size_t)(bh * 64 + t) * 4 + f) * 512 + lane2 * 8 + j] = val;
        } else {
          const int st = d >> 4;
          const int lane2 = ((d >> 3) & 1) * 32 + (nn & 31);
          const int j = d & 7;
          const size_t idx = ((size_t)(bh * 64 + t) * 4 + st) * 512 + lane2 * 8 + j;
          if (which == 0) Qo[idx] = val; else Ko[idx] = val;
        }
      }
    }
  }
}

// ---------------- 3) causal flash attention: fixed-max, 4-way split-k ----------------
// 1024 blocks x 256 thr (4 waves). Block = one q-tile pair (jj, 63-jj) -> exactly
// 65 k-tiles, split stride-4 across the 4 waves. Fixed softmax max (=0) ->
// partials merge by pure addition in LDS. bid%8 == head%8 pins K/V to one XCD L2.
// Q/K/V read from FRAGMENT-ORDER global layout: every load is lane-contiguous
// (16B/lane, 1KB/instr) -- r5's 128B/4KB-strided gathers split each load into
// ~32 L1 transactions and saturated the per-CU memory pipe (wave-count-invariant
// 2800 cy/tile with VALUBusy 20%, MfmaUtil 8.5%).
__global__ __launch_bounds__(256)
void attn4_kernel(const u16* __restrict__ Qb, const u16* __restrict__ Kb,
                  const u16* __restrict__ Vt, u16* __restrict__ Ctx) {
  __shared__ float mbuf[4][32][64];   // [wave][q][d], chunk-XOR-swizzled
  __shared__ float lbuf[4][32];

  const int tid = threadIdx.x;
  const int lane = tid & 63;
  const int kw = tid >> 6;             // wave = split-k slot 0..3
  const int ql = lane & 31;
  const int hi = lane >> 5;
  const int bid = blockIdx.x;
  const int c = bid & 7;
  const int r = bid >> 3;              // 0..127
  const int jj = r & 31;               // pair index
  const int bh = c + 8 * (r >> 5);     // 0..31
  const int b = bh >> 4, h = bh & 15;

  const u16* Qf = Qb + (size_t)bh * 64 * 2048;
  const u16* Kf = Kb + (size_t)bh * 64 * 2048;
  const u16* Vf = Vt + (size_t)bh * 64 * 2048;
  const int lofs = lane * 8;

  #pragma unroll 1
  for (int pass = 0; pass < 2; ++pass) {
    const int qt = pass ? (63 - jj) : jj;
    const int qb0 = qt * 32;

    bf16x8 qf[4];
    {
      const u16* qp = Qf + (size_t)qt * 2048 + lofs;
      #pragma unroll
      for (int st = 0; st < 4; ++st) qf[st] = *(const bf16x8*)(qp + st * 512);
    }

    f32x16 ctx0 = {0,0,0,0,0,0,0,0,0,0,0,0,0,0,0,0};
    f32x16 ctx1 = {0,0,0,0,0,0,0,0,0,0,0,0,0,0,0,0};
    float lacc[4] = {0.f, 0.f, 0.f, 0.f};

    bf16x8 kf[4], vf[4];
    if (kw <= qt) {
      // prologue load: tile kw
      {
        const u16* kp = Kf + (size_t)kw * 2048 + lofs;
        const u16* vp = Vf + (size_t)kw * 2048 + lofs;
        #pragma unroll
        for (int st = 0; st < 4; ++st) kf[st] = *(const bf16x8*)(kp + st * 512);
        #pragma unroll
        for (int f = 0; f < 4; ++f) vf[f] = *(const bf16x8*)(vp + f * 512);
      }
      #pragma unroll 1
      for (int t = kw; t <= qt; t += 4) {
        // ---- QK^T (S^T: key-in-reg, q-in-lane) ----
        f32x16 s = {0,0,0,0,0,0,0,0,0,0,0,0,0,0,0,0};
        #pragma unroll
        for (int st = 0; st < 4; ++st)
          s = __builtin_amdgcn_mfma_f32_32x32x16_bf16(kf[st], qf[st], s, 0, 0, 0);

        // prefetch next tile's K (kf dead after QK); clamped reload on last iter
        const int tn = (t + 4 <= qt) ? (t + 4) : qt;
        {
          const u16* kp = Kf + (size_t)tn * 2048 + lofs;
          #pragma unroll
          for (int st = 0; st < 4; ++st) kf[st] = *(const bf16x8*)(kp + st * 512);
        }

        // ---- softmax (fixed max = 0) ----
        float p[16];
        if (t == qt) {  // diagonal tile: causal mask (wave-uniform branch)
          #pragma unroll
          for (int cr = 0; cr < 16; ++cr) {
            const int kl = ((cr & 3) + 8 * (cr >> 2)) + 4 * hi;
            p[cr] = (kl > ql) ? 0.f : fexp2(s[cr]);
          }
        } else {
          #pragma unroll
          for (int cr = 0; cr < 16; ++cr) p[cr] = fexp2(s[cr]);
        }
        #pragma unroll
        for (int cr = 0; cr < 16; ++cr) lacc[cr & 3] += p[cr];

        // ---- PV: fragment k-order baked into V's stored layout ----
        #pragma unroll
        for (int ks = 0; ks < 2; ++ks) {
          uint4 pw;
          pw.x = cvtpk(p[ks * 8 + 0], p[ks * 8 + 1]);
          pw.y = cvtpk(p[ks * 8 + 2], p[ks * 8 + 3]);
          pw.z = cvtpk(p[ks * 8 + 4], p[ks * 8 + 5]);
          pw.w = cvtpk(p[ks * 8 + 6], p[ks * 8 + 7]);
          union { uint4 u; bf16x8 v; } pa; pa.u = pw;
          ctx0 = __builtin_amdgcn_mfma_f32_32x32x16_bf16(vf[ks * 2 + 0], pa.v, ctx0, 0, 0, 0);
          ctx1 = __builtin_amdgcn_mfma_f32_32x32x16_bf16(vf[ks * 2 + 1], pa.v, ctx1, 0, 0, 0);
        }

        // prefetch next tile's V (vf dead after PV)
        {
          const u16* vp = Vf + (size_t)tn * 2048 + lofs;
          #pragma unroll
          for (int f = 0; f < 4; ++f) vf[f] = *(const bf16x8*)(vp + f * 512);
        }
      }
    }

    // ---- 4-way split-k merge (fixed max -> pure addition) ----
    const float lloc = (lacc[0] + lacc[1]) + (lacc[2] + lacc[3]);
    const float lwv = lloc + swap32f(lloc);

    // write partial ctx: chunk ch = d/4, stored at ch ^ (q&15) (bank-conflict-free)
    #pragma unroll
    for (int grp = 0; grp < 4; ++grp) {
      const int ch = grp * 2 + hi;
      f32x4 t0 = {ctx0[grp * 4 + 0], ctx0[grp * 4 + 1], ctx0[grp * 4 + 2], ctx0[grp * 4 + 3]};
      f32x4 t1 = {ctx1[grp * 4 + 0], ctx1[grp * 4 + 1], ctx1[grp * 4 + 2], ctx1[grp * 4 + 3]};
      *(f32x4*)&mbuf[kw][ql][(ch ^ ql) * 4 & 63]       = t0;
      *(f32x4*)&mbuf[kw][ql][((ch + 8) ^ ql) * 4 & 63] = t1;
    }
    if (lane < 32) lbuf[kw][ql] = lwv;
    __syncthreads();

    // each wave sums d-slice [kw*16 + hi*8, +8) over the 4 partials
    {
      const int ch0 = kw * 4 + hi * 2;
      f32x4 a0 = {0.f, 0.f, 0.f, 0.f}, a1 = {0.f, 0.f, 0.f, 0.f};
      #pragma unroll
      for (int p2 = 0; p2 < 4; ++p2) {
        a0 += *(const f32x4*)&mbuf[p2][ql][(ch0 ^ ql) * 4 & 63];
        a1 += *(const f32x4*)&mbuf[p2][ql][((ch0 + 1) ^ ql) * 4 & 63];
      }
      const float lt = (lbuf[0][ql] + lbuf[1][ql]) + (lbuf[2][ql] + lbuf[3][ql]);
      const float inv = __builtin_amdgcn_rcpf(lt);
      uint4 pw;
      pw.x = cvtpk(a0[0] * inv, a0[1] * inv);
      pw.y = cvtpk(a0[2] * inv, a0[3] * inv);
      pw.z = cvtpk(a1[0] * inv, a1[1] * inv);
      pw.w = cvtpk(a1[2] * inv, a1[3] * inv);
      *(uint4*)(Ctx + (size_t)(b * SEQ + qb0 + ql) * 1024 + h * 64 + kw * 16 + hi * 8) = pw;
    }
    __syncthreads();  // protect mbuf/lbuf reuse in next pass
  }
}

// ---------------- 4) output projection + bias (fp32 out) ----------------
__global__ __launch_bounds__(256)
void gemm_out_kernel(const u16* __restrict__ Ctx, const u16* __restrict__ WoT,
                     const float* __restrict__ bo, float* __restrict__ out) {
  __shared__ u16 As[128 * 32];
  __shared__ u16 Bs[128 * 32];
  const int tid = threadIdx.x;
  const int lane = tid & 63;
  const int w = tid >> 6;
  const int bm = blockIdx.x * 128;
  const int bn = blockIdx.y * 128;
  const int wr = w >> 1, wc = w & 1;
  const int g = lane >> 4, lm = lane & 15;
  const int srow = lane >> 2;
  const int scol = (lane & 3) * 8;

  const f32x4 zero = {0.f, 0.f, 0.f, 0.f};
  f32x4 acc[4][4];
  #pragma unroll
  for (int i = 0; i < 4; ++i)
    #pragma unroll
    for (int n = 0; n < 4; ++n) acc[i][n] = zero;

  for (int k0 = 0; k0 < D_IN; k0 += 32) {
    __syncthreads();
    #pragma unroll
    for (int L = 0; L < 2; ++L) {
      const int chunk = w * 2 + L;
      const int r = chunk * 16 + srow;
      GLD_LDS16(Ctx + (size_t)(bm + r) * D_IN + k0 + scol, As + chunk * 512);
      GLD_LDS16(WoT + (size_t)(bn + r) * D_IN + k0 + scol, Bs + chunk * 512);
    }
    __syncthreads();

    bf16x8 af[4], bf[4];
    #pragma unroll
    for (int i = 0; i < 4; ++i)
      af[i] = *(const bf16x8*)(As + (wr * 64 + i * 16 + lm) * 32 + g * 8);
    #pragma unroll
    for (int n = 0; n < 4; ++n)
      bf[n] = *(const bf16x8*)(Bs + (wc * 64 + n * 16 + lm) * 32 + g * 8);
    #pragma unroll
    for (int i = 0; i < 4; ++i)
      #pragma unroll
      for (int n = 0; n < 4; ++n)
        acc[i][n] = __builtin_amdgcn_mfma_f32_16x16x32_bf16(af[i], bf[n], acc[i][n], 0, 0, 0);
  }

  #pragma unroll
  for (int i = 0; i < 4; ++i)
    #pragma unroll
    for (int n = 0; n < 4; ++n)
      #pragma unroll
      for (int r = 0; r < 4; ++r) {
        const int m = bm + wr * 64 + i * 16 + g * 4 + r;
        const int cidx = bn + wc * 64 + n * 16 + lm;
        out[(size_t)m * 1024 + cidx] = acc[i][n][r] + bo[cidx];
      }
}

extern "C" void kernel_launch(void* const* d_in, const int* in_sizes, int n_in,
                              void* d_out, int out_size, void* d_ws, size_t ws_size,
                              hipStream_t stream) {
  (void)in_sizes; (void)n_in; (void)out_size; (void)ws_size;
  const float* x  = (const float*)d_in[0];
  const float* Wq = (const float*)d_in[1];
  const float* Wk = (const float*)d_in[2];
  const float* Wv = (const float*)d_in[3];
  const float* Wo = (const float*)d_in[4];
  const float* bo = (const float*)d_in[5];
  float* out = (float*)d_out;

  char* ws = (char*)d_ws;
  u16* xb  = (u16*)(ws);
  u16* WqT = (u16*)(ws + (8u << 20));
  u16* WkT = (u16*)(ws + (10u << 20));
  u16* WvT = (u16*)(ws + (12u << 20));
  u16* WoT = (u16*)(ws + (14u << 20));
  u16* Qb  = (u16*)(ws + (16u << 20));
  u16* Kb  = (u16*)(ws + (24u << 20));
  u16* Vt  = (u16*)(ws + (32u << 20));
  u16* Ctx = xb;  // xb fully consumed by gemm_qkv before attn writes Ctx

  prep_kernel<<<dim3(8192), 256, 0, stream>>>(x, xb, Wq, Wk, Wv, Wo, WqT, WkT, WvT, WoT);
  gemm_qkv_kernel<<<dim3(32, 8, 3), 256, 0, stream>>>(xb, WqT, WkT, WvT, Qb, Kb, Vt);
  attn4_kernel<<<dim3(1024), 256, 0, stream>>>(Qb, Kb, Vt, Ctx);
  gemm_out_kernel<<<dim3(32, 8), 256, 0, stream>>>(Ctx, WoT, bo, out);
}